// Round 2
// baseline (2301.416 us; speedup 1.0000x reference)
//
#include <hip/hip_runtime.h>
#include <cstddef>
#include <cstdint>

#define N_NODES 100000
#define N_EDGES 3200000
#define D 256
#define SCAN_BLOCKS ((N_NODES + 1023) / 1024)  // 98

// ---------------- degree histogram ----------------
__global__ __launch_bounds__(256) void hist_kernel(const int* __restrict__ row,
                                                   int* __restrict__ deg) {
    int e = blockIdx.x * 256 + threadIdx.x;
    if (e < N_EDGES) atomicAdd(&deg[row[e]], 1);
}

// ---------------- scan stage A: per-block exclusive scan + block sums ----------------
__global__ __launch_bounds__(1024) void scanA_kernel(const int* __restrict__ deg,
                                                     int* __restrict__ rowptr,
                                                     int* __restrict__ blocksum) {
    __shared__ int waveTot[16];
    __shared__ int waveOff[16];
    const int tid  = threadIdx.x;
    const int lane = tid & 63;
    const int wv   = tid >> 6;
    const int idx  = blockIdx.x * 1024 + tid;
    int v = (idx < N_NODES) ? deg[idx] : 0;
    int inc = v;
#pragma unroll
    for (int off = 1; off < 64; off <<= 1) {
        int up = __shfl_up(inc, off, 64);
        if (lane >= off) inc += up;
    }
    if (lane == 63) waveTot[wv] = inc;
    __syncthreads();
    if (tid == 0) {
        int run = 0;
#pragma unroll
        for (int w = 0; w < 16; ++w) { waveOff[w] = run; run += waveTot[w]; }
        blocksum[blockIdx.x] = run;
    }
    __syncthreads();
    if (idx < N_NODES) rowptr[idx] = waveOff[wv] + (inc - v);
}

// ---------------- scan stage B: scan the 98 block sums (tiny, serial) ----------------
__global__ void scanB_kernel(int* __restrict__ blocksum, int* __restrict__ rowptr) {
    if (threadIdx.x == 0 && blockIdx.x == 0) {
        int run = 0;
        for (int b = 0; b < SCAN_BLOCKS; ++b) {
            int t = blocksum[b];
            blocksum[b] = run;
            run += t;
        }
        rowptr[N_NODES] = run;
    }
}

// ---------------- scan stage C: add block offsets ----------------
__global__ __launch_bounds__(1024) void scanC_kernel(int* __restrict__ rowptr,
                                                     const int* __restrict__ blocksum,
                                                     int* __restrict__ cursor) {
    const int idx = blockIdx.x * 1024 + threadIdx.x;
    if (idx < N_NODES) {
        int v = rowptr[idx] + blocksum[blockIdx.x];
        rowptr[idx] = v;
        cursor[idx] = v;
    }
}

// ---------------- scatter edges into CSR order (packed col+val) ----------------
__global__ __launch_bounds__(256) void scatter_kernel(const int* __restrict__ row,
                                                      const int* __restrict__ col,
                                                      const float* __restrict__ val,
                                                      int* __restrict__ cursor,
                                                      int2* __restrict__ cedge) {
    int e = blockIdx.x * 256 + threadIdx.x;
    if (e < N_EDGES) {
        int r = row[e];
        int pos = atomicAdd(&cursor[r], 1);
        cedge[pos] = make_int2(col[e], __float_as_int(val[e]));
    }
}

// ---------------- CSR SpMM: one wave (64 lanes) per node, float4 per lane ----------------
__global__ __launch_bounds__(256) void spmm_kernel(const int* __restrict__ rowptr,
                                                   const int2* __restrict__ cedge,
                                                   const float* __restrict__ h,
                                                   float* __restrict__ out) {
    const int node = (blockIdx.x << 2) + (threadIdx.x >> 6);
    const int lane = threadIdx.x & 63;
    if (node >= N_NODES) return;
    const float4* __restrict__ h4 = (const float4*)h;  // row stride 64 float4
    int k = rowptr[node];
    const int end = rowptr[node + 1];
    float4 acc = make_float4(0.f, 0.f, 0.f, 0.f);
    for (; k + 4 <= end; k += 4) {
        int2 e0 = cedge[k];
        int2 e1 = cedge[k + 1];
        int2 e2 = cedge[k + 2];
        int2 e3 = cedge[k + 3];
        float4 a0 = h4[(size_t)e0.x * 64 + lane];
        float4 a1 = h4[(size_t)e1.x * 64 + lane];
        float4 a2 = h4[(size_t)e2.x * 64 + lane];
        float4 a3 = h4[(size_t)e3.x * 64 + lane];
        float v0 = __int_as_float(e0.y);
        float v1 = __int_as_float(e1.y);
        float v2 = __int_as_float(e2.y);
        float v3 = __int_as_float(e3.y);
        acc.x = fmaf(v0, a0.x, acc.x); acc.y = fmaf(v0, a0.y, acc.y);
        acc.z = fmaf(v0, a0.z, acc.z); acc.w = fmaf(v0, a0.w, acc.w);
        acc.x = fmaf(v1, a1.x, acc.x); acc.y = fmaf(v1, a1.y, acc.y);
        acc.z = fmaf(v1, a1.z, acc.z); acc.w = fmaf(v1, a1.w, acc.w);
        acc.x = fmaf(v2, a2.x, acc.x); acc.y = fmaf(v2, a2.y, acc.y);
        acc.z = fmaf(v2, a2.z, acc.z); acc.w = fmaf(v2, a2.w, acc.w);
        acc.x = fmaf(v3, a3.x, acc.x); acc.y = fmaf(v3, a3.y, acc.y);
        acc.z = fmaf(v3, a3.z, acc.z); acc.w = fmaf(v3, a3.w, acc.w);
    }
    for (; k < end; ++k) {
        int2 e = cedge[k];
        float4 a = h4[(size_t)e.x * 64 + lane];
        float v = __int_as_float(e.y);
        acc.x = fmaf(v, a.x, acc.x); acc.y = fmaf(v, a.y, acc.y);
        acc.z = fmaf(v, a.z, acc.z); acc.w = fmaf(v, a.w, acc.w);
    }
    ((float4*)out)[(size_t)node * 64 + lane] = acc;
}

// ---------------- concat-GEMM: out = act([A1|A2] @ W + bias) ----------------
// 64 rows x 256 cols (full width) per block; 256 threads, 4x16 micro-tile.
// A is read exactly once from HBM; W re-reads hit L2 (512 KB).
template <bool RELU>
__global__ __launch_bounds__(256) void gemm_kernel(const float* __restrict__ A1,
                                                   const float* __restrict__ A2,
                                                   const float* __restrict__ W,
                                                   const float* __restrict__ bias,
                                                   float* __restrict__ out) {
    __shared__ float As[16][68];   // [k][m] row stride 68 (16B-aligned, conflict-free)
    __shared__ float Bs[16][260];  // [k][j]
    const int tid = threadIdx.x;
    const int tx = tid & 15;   // 16 cols each
    const int ty = tid >> 4;   // 4 rows each
    const int bm = blockIdx.x * 64;
    const int la_k = tid & 15;
    const int la_m = tid >> 4;
    const int lb_k = tid >> 4;          // 16 k rows
    const int lb_j = (tid & 15) * 16;   // 16-col chunk base

    float acc[4][16] = {};

    for (int t = 0; t < 32; ++t) {
        const float* __restrict__ A = (t < 16) ? A1 : A2;
        const int k0  = (t & 15) * 16;  // column offset within A
        const int wk0 = t * 16;         // row offset within W
        // A tile: As[k][m] = A[bm+m][k0+k]
#pragma unroll
        for (int p = 0; p < 4; ++p) {
            int m = la_m + p * 16;
            int r = bm + m;
            if (r >= N_NODES) r = N_NODES - 1;  // clamp (stores guarded)
            As[la_k][m] = A[(size_t)r * D + k0 + la_k];
        }
        // B tile: Bs[k][j] = W[wk0+k][j], 16 floats per thread via float4
#pragma unroll
        for (int q = 0; q < 4; ++q) {
            float4 w4 = *reinterpret_cast<const float4*>(&W[(size_t)(wk0 + lb_k) * D + lb_j + 4 * q]);
            *reinterpret_cast<float4*>(&Bs[lb_k][lb_j + 4 * q]) = w4;
        }
        __syncthreads();
#pragma unroll
        for (int kk = 0; kk < 16; ++kk) {
            float4 av = *reinterpret_cast<const float4*>(&As[kk][ty * 4]);
            float a[4] = {av.x, av.y, av.z, av.w};
            float b[16];
#pragma unroll
            for (int q = 0; q < 4; ++q) {
                float4 bv = *reinterpret_cast<const float4*>(&Bs[kk][tx * 16 + 4 * q]);
                b[4 * q] = bv.x; b[4 * q + 1] = bv.y; b[4 * q + 2] = bv.z; b[4 * q + 3] = bv.w;
            }
#pragma unroll
            for (int i2 = 0; i2 < 4; ++i2)
#pragma unroll
                for (int j2 = 0; j2 < 16; ++j2)
                    acc[i2][j2] = fmaf(a[i2], b[j2], acc[i2][j2]);
        }
        __syncthreads();
    }
    // epilogue: bias + optional relu, float4 stores
#pragma unroll
    for (int i2 = 0; i2 < 4; ++i2) {
        int r = bm + ty * 4 + i2;
        if (r < N_NODES) {
#pragma unroll
            for (int q = 0; q < 4; ++q) {
                int c = tx * 16 + 4 * q;
                float4 v;
                v.x = acc[i2][4 * q]     + bias[c];
                v.y = acc[i2][4 * q + 1] + bias[c + 1];
                v.z = acc[i2][4 * q + 2] + bias[c + 2];
                v.w = acc[i2][4 * q + 3] + bias[c + 3];
                if (RELU) {
                    v.x = fmaxf(v.x, 0.f); v.y = fmaxf(v.y, 0.f);
                    v.z = fmaxf(v.z, 0.f); v.w = fmaxf(v.w, 0.f);
                }
                *reinterpret_cast<float4*>(&out[(size_t)r * D + c]) = v;
            }
        }
    }
}

extern "C" void kernel_launch(void* const* d_in, const int* in_sizes, int n_in,
                              void* d_out, int out_size, void* d_ws, size_t ws_size,
                              hipStream_t stream) {
    const float* x     = (const float*)d_in[0];
    const int*   erow  = (const int*)d_in[1];
    const int*   ecol  = (const int*)d_in[2];
    const float* evalv = (const float*)d_in[3];
    const float* W1    = (const float*)d_in[4];
    const float* b1    = (const float*)d_in[5];
    const float* Wout  = (const float*)d_in[6];
    const float* bout  = (const float*)d_in[7];
    float* out = (float*)d_out;

    char* ws = (char*)d_ws;
    size_t off = 0;
    auto alloc = [&](size_t bytes) -> void* {
        void* p = ws + off;
        off += (bytes + 255) & ~(size_t)255;
        return p;
    };
    float* neigh    = (float*)alloc((size_t)N_NODES * D * sizeof(float));   // 102.4 MB
    float* h1       = (float*)alloc((size_t)N_NODES * D * sizeof(float));   // 102.4 MB
    int*   rowptr   = (int*)alloc((size_t)(N_NODES + 1) * sizeof(int));
    int*   deg      = (int*)alloc((size_t)N_NODES * sizeof(int));
    int*   cursor   = (int*)alloc((size_t)N_NODES * sizeof(int));
    int*   blocksum = (int*)alloc((size_t)SCAN_BLOCKS * sizeof(int));
    int2*  cedge    = (int2*)alloc((size_t)N_EDGES * sizeof(int2));         // 25.6 MB

    // 1. build CSR (reused by both SpMM layers)
    hipMemsetAsync(deg, 0, (size_t)N_NODES * sizeof(int), stream);
    hist_kernel<<<(N_EDGES + 255) / 256, 256, 0, stream>>>(erow, deg);
    scanA_kernel<<<SCAN_BLOCKS, 1024, 0, stream>>>(deg, rowptr, blocksum);
    scanB_kernel<<<1, 64, 0, stream>>>(blocksum, rowptr);
    scanC_kernel<<<SCAN_BLOCKS, 1024, 0, stream>>>(rowptr, blocksum, cursor);
    scatter_kernel<<<(N_EDGES + 255) / 256, 256, 0, stream>>>(erow, ecol, evalv,
                                                              cursor, cedge);
    // 2. layer 1: neigh = A @ x ; h1 = relu([x|neigh] @ W1 + b1)
    spmm_kernel<<<(N_NODES + 3) / 4, 256, 0, stream>>>(rowptr, cedge, x, neigh);
    dim3 ggrid((N_NODES + 63) / 64);
    gemm_kernel<true><<<ggrid, 256, 0, stream>>>(x, neigh, W1, b1, h1);
    // 3. layer 2: neigh2 = A @ h1 ; out = [h1|neigh2] @ Wout + bout
    spmm_kernel<<<(N_NODES + 3) / 4, 256, 0, stream>>>(rowptr, cedge, h1, neigh);
    gemm_kernel<false><<<ggrid, 256, 0, stream>>>(h1, neigh, Wout, bout, out);
}

// Round 3
// 1290.769 us; speedup vs baseline: 1.7830x; 1.7830x over previous
//
#include <hip/hip_runtime.h>
#include <cstddef>
#include <cstdint>

#define N_NODES 100000
#define N_EDGES 3200000
#define D 256
#define SCAN_BLOCKS ((N_NODES + 1023) / 1024)  // 98

typedef __attribute__((ext_vector_type(8))) short bf16x8;
typedef __attribute__((ext_vector_type(4))) float f32x4;

__device__ __forceinline__ ushort f2b(float f) {  // f32 -> bf16 RNE
    unsigned u = __float_as_uint(f);
    return (ushort)((u + 0x7fffu + ((u >> 16) & 1u)) >> 16);
}

// ---------------- degree histogram ----------------
__global__ __launch_bounds__(256) void hist_kernel(const int* __restrict__ row,
                                                   int* __restrict__ deg) {
    int e = blockIdx.x * 256 + threadIdx.x;
    if (e < N_EDGES) atomicAdd(&deg[row[e]], 1);
}

// ---------------- scan stage A ----------------
__global__ __launch_bounds__(1024) void scanA_kernel(const int* __restrict__ deg,
                                                     int* __restrict__ rowptr,
                                                     int* __restrict__ blocksum) {
    __shared__ int waveTot[16];
    __shared__ int waveOff[16];
    const int tid  = threadIdx.x;
    const int lane = tid & 63;
    const int wv   = tid >> 6;
    const int idx  = blockIdx.x * 1024 + tid;
    int v = (idx < N_NODES) ? deg[idx] : 0;
    int inc = v;
#pragma unroll
    for (int off = 1; off < 64; off <<= 1) {
        int up = __shfl_up(inc, off, 64);
        if (lane >= off) inc += up;
    }
    if (lane == 63) waveTot[wv] = inc;
    __syncthreads();
    if (tid == 0) {
        int run = 0;
#pragma unroll
        for (int w = 0; w < 16; ++w) { waveOff[w] = run; run += waveTot[w]; }
        blocksum[blockIdx.x] = run;
    }
    __syncthreads();
    if (idx < N_NODES) rowptr[idx] = waveOff[wv] + (inc - v);
}

// ---------------- scan stage B ----------------
__global__ void scanB_kernel(int* __restrict__ blocksum, int* __restrict__ rowptr) {
    if (threadIdx.x == 0 && blockIdx.x == 0) {
        int run = 0;
        for (int b = 0; b < SCAN_BLOCKS; ++b) {
            int t = blocksum[b];
            blocksum[b] = run;
            run += t;
        }
        rowptr[N_NODES] = run;
    }
}

// ---------------- scan stage C ----------------
__global__ __launch_bounds__(1024) void scanC_kernel(int* __restrict__ rowptr,
                                                     const int* __restrict__ blocksum,
                                                     int* __restrict__ cursor) {
    const int idx = blockIdx.x * 1024 + threadIdx.x;
    if (idx < N_NODES) {
        int v = rowptr[idx] + blocksum[blockIdx.x];
        rowptr[idx] = v;
        cursor[idx] = v;
    }
}

// ---------------- scatter edges into CSR order ----------------
__global__ __launch_bounds__(256) void scatter_kernel(const int* __restrict__ row,
                                                      const int* __restrict__ col,
                                                      const float* __restrict__ val,
                                                      int* __restrict__ cursor,
                                                      int2* __restrict__ cedge) {
    int e = blockIdx.x * 256 + threadIdx.x;
    if (e < N_EDGES) {
        int r = row[e];
        int pos = atomicAdd(&cursor[r], 1);
        cedge[pos] = make_int2(col[e], __float_as_int(val[e]));
    }
}

// ---------------- f32 -> bf16 elementwise (4 elems/thread) ----------------
__global__ __launch_bounds__(256) void cvt_kernel(const float* __restrict__ in,
                                                  ushort* __restrict__ out, int n4) {
    int i = blockIdx.x * 256 + threadIdx.x;
    if (i < n4) {
        float4 v = ((const float4*)in)[i];
        uint2 p;
        p.x = (unsigned)f2b(v.x) | ((unsigned)f2b(v.y) << 16);
        p.y = (unsigned)f2b(v.z) | ((unsigned)f2b(v.w) << 16);
        ((uint2*)out)[i] = p;
    }
}

// ---------------- W [512][256] f32 -> Wt [256][512] bf16 (transpose) ----------------
__global__ __launch_bounds__(256) void wtrans_kernel(const float* __restrict__ W,
                                                     ushort* __restrict__ Wt) {
    int t = blockIdx.x * 256 + threadIdx.x;  // 512*256 threads
    int j = t & 255;
    int k = t >> 8;
    Wt[(size_t)j * 512 + k] = f2b(W[(size_t)k * 256 + j]);
}

// ---------------- CSR SpMM (bf16 features): one wave per node ----------------
__global__ __launch_bounds__(256) void spmm_kernel(const int* __restrict__ rowptr,
                                                   const int2* __restrict__ cedge,
                                                   const ushort* __restrict__ h,
                                                   ushort* __restrict__ outb) {
    const int node = (blockIdx.x << 2) + (threadIdx.x >> 6);  // grid*4 == N_NODES
    const int lane = threadIdx.x & 63;
    const uint2* __restrict__ h2 = (const uint2*)h;  // 4 bf16 per uint2, row = 64 uint2
    int k = rowptr[node];
    const int end = rowptr[node + 1];
    float a0 = 0.f, a1 = 0.f, a2 = 0.f, a3 = 0.f;
#define EDGE_FMA(e, d)                                              \
    {                                                               \
        float v = __int_as_float((e).y);                            \
        a0 = fmaf(v, __uint_as_float((d).x << 16), a0);             \
        a1 = fmaf(v, __uint_as_float((d).x & 0xffff0000u), a1);     \
        a2 = fmaf(v, __uint_as_float((d).y << 16), a2);             \
        a3 = fmaf(v, __uint_as_float((d).y & 0xffff0000u), a3);     \
    }
    for (; k + 4 <= end; k += 4) {
        int2 e0 = cedge[k];
        int2 e1 = cedge[k + 1];
        int2 e2 = cedge[k + 2];
        int2 e3 = cedge[k + 3];
        uint2 d0 = h2[(size_t)e0.x * 64 + lane];
        uint2 d1 = h2[(size_t)e1.x * 64 + lane];
        uint2 d2 = h2[(size_t)e2.x * 64 + lane];
        uint2 d3 = h2[(size_t)e3.x * 64 + lane];
        EDGE_FMA(e0, d0)
        EDGE_FMA(e1, d1)
        EDGE_FMA(e2, d2)
        EDGE_FMA(e3, d3)
    }
    for (; k < end; ++k) {
        int2 e = cedge[k];
        uint2 d = h2[(size_t)e.x * 64 + lane];
        EDGE_FMA(e, d)
    }
#undef EDGE_FMA
    uint2 p;
    p.x = (unsigned)f2b(a0) | ((unsigned)f2b(a1) << 16);
    p.y = (unsigned)f2b(a2) | ((unsigned)f2b(a3) << 16);
    ((uint2*)outb)[(size_t)node * 64 + lane] = p;
}

// ---------------- MFMA concat-GEMM ----------------
// C[M,256] = act([A1|A2] @ W + bias), A1/A2 bf16 [M][256], Wt bf16 [256][512]
// (Wt[j][k] = W[k][j]). One wave computes 16 rows x 256 cols; no LDS staging:
// A-frags loaded direct from HBM (read exactly once), B-frags from L2-resident Wt.
// OUT_BF16: relu + bf16 store (layer 1). else: f32 float4 store (output layer).
template <bool OUT_BF16>
__global__ __launch_bounds__(128) void gemm_mfma_kernel(const ushort* __restrict__ A1,
                                                        const ushort* __restrict__ A2,
                                                        const ushort* __restrict__ Wt,
                                                        const float* __restrict__ bias,
                                                        void* __restrict__ outp) {
    __shared__ float lds[2][16][260];  // per-wave repack tile (stride 260: conflict-free)
    const int wid  = threadIdx.x >> 6;
    const int lane = threadIdx.x & 63;
    const int wave = blockIdx.x * 2 + wid;
    const int row0 = wave * 16;        // 6250 waves * 16 = 100000 exactly
    const int lr = lane & 15;          // fragment row (A) / col (B) index
    const int lk = (lane >> 4) * 8;    // fragment k offset

    f32x4 acc[16];
#pragma unroll
    for (int c = 0; c < 16; ++c) acc[c] = (f32x4){0.f, 0.f, 0.f, 0.f};

#pragma unroll 1
    for (int t8 = 0; t8 < 8; ++t8) {  // K-steps over A1 half
        bf16x8 af = *(const bf16x8*)(A1 + (size_t)(row0 + lr) * 256 + t8 * 32 + lk);
#pragma unroll
        for (int c = 0; c < 16; ++c) {
            bf16x8 bf_ = *(const bf16x8*)(Wt + ((size_t)(c * 16 + lr) << 9) + t8 * 32 + lk);
            acc[c] = __builtin_amdgcn_mfma_f32_16x16x32_bf16(af, bf_, acc[c], 0, 0, 0);
        }
    }
#pragma unroll 1
    for (int t8 = 0; t8 < 8; ++t8) {  // K-steps over A2 half (W rows 256..511)
        bf16x8 af = *(const bf16x8*)(A2 + (size_t)(row0 + lr) * 256 + t8 * 32 + lk);
#pragma unroll
        for (int c = 0; c < 16; ++c) {
            bf16x8 bf_ = *(const bf16x8*)(Wt + ((size_t)(c * 16 + lr) << 9) + 256 + t8 * 32 + lk);
            acc[c] = __builtin_amdgcn_mfma_f32_16x16x32_bf16(af, bf_, acc[c], 0, 0, 0);
        }
    }

    // D layout: D[i][j], j = lane&15, i = (lane>>4)*4 + reg  (guide §3, m89-verified)
    float (*L)[260] = lds[wid];
#pragma unroll
    for (int c = 0; c < 16; ++c) {
        float bv = bias[c * 16 + lr];
#pragma unroll
        for (int r = 0; r < 4; ++r) {
            float v = acc[c][r] + bv;
            if (OUT_BF16) v = fmaxf(v, 0.f);
            L[(lane >> 4) * 4 + r][c * 16 + lr] = v;
        }
    }
    __syncthreads();
    if (OUT_BF16) {
        ushort* out = (ushort*)outp;
#pragma unroll
        for (int i = 0; i < 16; ++i) {
            float4 v = *(const float4*)&L[i][lane * 4];
            uint2 p;
            p.x = (unsigned)f2b(v.x) | ((unsigned)f2b(v.y) << 16);
            p.y = (unsigned)f2b(v.z) | ((unsigned)f2b(v.w) << 16);
            *(uint2*)&out[(size_t)(row0 + i) * 256 + lane * 4] = p;
        }
    } else {
        float* out = (float*)outp;
#pragma unroll
        for (int i = 0; i < 16; ++i) {
            float4 v = *(const float4*)&L[i][lane * 4];
            *(float4*)&out[(size_t)(row0 + i) * 256 + lane * 4] = v;
        }
    }
}

extern "C" void kernel_launch(void* const* d_in, const int* in_sizes, int n_in,
                              void* d_out, int out_size, void* d_ws, size_t ws_size,
                              hipStream_t stream) {
    const float* x     = (const float*)d_in[0];
    const int*   erow  = (const int*)d_in[1];
    const int*   ecol  = (const int*)d_in[2];
    const float* evalv = (const float*)d_in[3];
    const float* W1    = (const float*)d_in[4];
    const float* b1    = (const float*)d_in[5];
    const float* Wout  = (const float*)d_in[6];
    const float* bout  = (const float*)d_in[7];
    float* out = (float*)d_out;

    char* ws = (char*)d_ws;
    size_t off = 0;
    auto alloc = [&](size_t bytes) -> void* {
        void* p = ws + off;
        off += (bytes + 255) & ~(size_t)255;
        return p;
    };
    ushort* xb       = (ushort*)alloc((size_t)N_NODES * D * 2);   // 51.2 MB
    ushort* h1b      = (ushort*)alloc((size_t)N_NODES * D * 2);   // 51.2 MB
    ushort* neighb   = (ushort*)alloc((size_t)N_NODES * D * 2);   // 51.2 MB
    ushort* W1t      = (ushort*)alloc((size_t)512 * 256 * 2);
    ushort* Woutt    = (ushort*)alloc((size_t)512 * 256 * 2);
    int*    rowptr   = (int*)alloc((size_t)(N_NODES + 1) * sizeof(int));
    int*    deg      = (int*)alloc((size_t)N_NODES * sizeof(int));
    int*    cursor   = (int*)alloc((size_t)N_NODES * sizeof(int));
    int*    blocksum = (int*)alloc((size_t)SCAN_BLOCKS * sizeof(int));
    int2*   cedge    = (int2*)alloc((size_t)N_EDGES * sizeof(int2));  // 25.6 MB

    // converts (independent of CSR)
    cvt_kernel<<<(N_NODES * D / 4 + 255) / 256, 256, 0, stream>>>(x, xb, N_NODES * D / 4);
    wtrans_kernel<<<512, 256, 0, stream>>>(W1, W1t);
    wtrans_kernel<<<512, 256, 0, stream>>>(Wout, Woutt);

    // build CSR (reused by both SpMM layers)
    hipMemsetAsync(deg, 0, (size_t)N_NODES * sizeof(int), stream);
    hist_kernel<<<(N_EDGES + 255) / 256, 256, 0, stream>>>(erow, deg);
    scanA_kernel<<<SCAN_BLOCKS, 1024, 0, stream>>>(deg, rowptr, blocksum);
    scanB_kernel<<<1, 64, 0, stream>>>(blocksum, rowptr);
    scanC_kernel<<<SCAN_BLOCKS, 1024, 0, stream>>>(rowptr, blocksum, cursor);
    scatter_kernel<<<(N_EDGES + 255) / 256, 256, 0, stream>>>(erow, ecol, evalv,
                                                              cursor, cedge);

    // layer 1
    spmm_kernel<<<N_NODES / 4, 256, 0, stream>>>(rowptr, cedge, xb, neighb);
    gemm_mfma_kernel<true><<<N_NODES / 32, 128, 0, stream>>>(xb, neighb, W1t, b1, h1b);
    // layer 2
    spmm_kernel<<<N_NODES / 4, 256, 0, stream>>>(rowptr, cedge, h1b, neighb);
    gemm_mfma_kernel<false><<<N_NODES / 32, 128, 0, stream>>>(h1b, neighb, Woutt, bout, out);
}

// Round 4
// 1183.253 us; speedup vs baseline: 1.9450x; 1.0909x over previous
//
#include <hip/hip_runtime.h>
#include <cstddef>
#include <cstdint>

#define N_NODES 100000
#define N_EDGES 3200000
#define D 256
#define SCAN_BLOCKS ((N_NODES + 1023) / 1024)  // 98
#define BSHIFT 9                                // 512 rows per bucket
#define NBUCK ((N_NODES + (1 << BSHIFT) - 1) >> BSHIFT)  // 196
#define EPB 4096                                // edges per pass-1 block

typedef __attribute__((ext_vector_type(8))) short bf16x8;
typedef __attribute__((ext_vector_type(4))) float f32x4;

__device__ __forceinline__ ushort f2b(float f) {  // f32 -> bf16 RNE
    unsigned u = __float_as_uint(f);
    return (ushort)((u + 0x7fffu + ((u >> 16) & 1u)) >> 16);
}

// ---------------- degree histogram ----------------
__global__ __launch_bounds__(256) void hist_kernel(const int* __restrict__ row,
                                                   int* __restrict__ deg) {
    int e = blockIdx.x * 256 + threadIdx.x;
    if (e < N_EDGES) atomicAdd(&deg[row[e]], 1);
}

// ---------------- scan stage A ----------------
__global__ __launch_bounds__(1024) void scanA_kernel(const int* __restrict__ deg,
                                                     int* __restrict__ rowptr,
                                                     int* __restrict__ blocksum) {
    __shared__ int waveTot[16];
    __shared__ int waveOff[16];
    const int tid  = threadIdx.x;
    const int lane = tid & 63;
    const int wv   = tid >> 6;
    const int idx  = blockIdx.x * 1024 + tid;
    int v = (idx < N_NODES) ? deg[idx] : 0;
    int inc = v;
#pragma unroll
    for (int off = 1; off < 64; off <<= 1) {
        int up = __shfl_up(inc, off, 64);
        if (lane >= off) inc += up;
    }
    if (lane == 63) waveTot[wv] = inc;
    __syncthreads();
    if (tid == 0) {
        int run = 0;
#pragma unroll
        for (int w = 0; w < 16; ++w) { waveOff[w] = run; run += waveTot[w]; }
        blocksum[blockIdx.x] = run;
    }
    __syncthreads();
    if (idx < N_NODES) rowptr[idx] = waveOff[wv] + (inc - v);
}

// ---------------- scan stage B ----------------
__global__ void scanB_kernel(int* __restrict__ blocksum, int* __restrict__ rowptr) {
    if (threadIdx.x == 0 && blockIdx.x == 0) {
        int run = 0;
        for (int b = 0; b < SCAN_BLOCKS; ++b) {
            int t = blocksum[b];
            blocksum[b] = run;
            run += t;
        }
        rowptr[N_NODES] = run;
    }
}

// ---------------- scan stage C ----------------
__global__ __launch_bounds__(1024) void scanC_kernel(int* __restrict__ rowptr,
                                                     const int* __restrict__ blocksum,
                                                     int* __restrict__ cursor) {
    const int idx = blockIdx.x * 1024 + threadIdx.x;
    if (idx < N_NODES) {
        int v = rowptr[idx] + blocksum[blockIdx.x];
        rowptr[idx] = v;
        cursor[idx] = v;
    }
}

// ---------------- bucket cursor init (bucket start = rowptr[b<<BSHIFT]) ----------------
__global__ void bucketinit_kernel(const int* __restrict__ rowptr,
                                  int* __restrict__ bucket_cursor) {
    int b = blockIdx.x * 256 + threadIdx.x;
    if (b < NBUCK) bucket_cursor[b] = rowptr[b << BSHIFT];
}

// ---------------- binned scatter pass 1: edges -> bucket-grouped staging ----------------
__global__ __launch_bounds__(256) void binpass1_kernel(const int* __restrict__ erow,
                                                       const int* __restrict__ ecol,
                                                       const float* __restrict__ evalv,
                                                       int* __restrict__ bucket_cursor,
                                                       int* __restrict__ srow,
                                                       int2* __restrict__ scolval) {
    __shared__ int cnt[NBUCK];
    __shared__ int lstart[NBUCK];
    __shared__ int gbase[NBUCK];
    __shared__ int wtot[4];
    __shared__ int woff[4];
    __shared__ int   lrow[EPB];   // 16 KB
    __shared__ int2  lcv[EPB];    // 32 KB
    const int tid = threadIdx.x;
    const size_t base = (size_t)blockIdx.x * EPB;
    for (int b = tid; b < NBUCK; b += 256) cnt[b] = 0;
    __syncthreads();
    int rows[16];
    int2 cv[16];
    int loff[16];
#pragma unroll
    for (int i = 0; i < 16; ++i) {
        size_t e = base + (size_t)i * 256 + tid;
        if (e < N_EDGES) {
            int r = erow[e];
            rows[i] = r;
            cv[i] = make_int2(ecol[e], __float_as_int(evalv[e]));
            loff[i] = atomicAdd(&cnt[r >> BSHIFT], 1);
        } else {
            rows[i] = -1;
        }
    }
    __syncthreads();
    // exclusive scan of cnt[0..NBUCK) over 256 threads
    {
        int b = tid;
        int v = (b < NBUCK) ? cnt[b] : 0;
        int lane = tid & 63, wv = tid >> 6;
        int inc = v;
#pragma unroll
        for (int off = 1; off < 64; off <<= 1) {
            int u = __shfl_up(inc, off, 64);
            if (lane >= off) inc += u;
        }
        if (lane == 63) wtot[wv] = inc;
        __syncthreads();
        if (tid == 0) {
            int run = 0;
#pragma unroll
            for (int w = 0; w < 4; ++w) { woff[w] = run; run += wtot[w]; }
        }
        __syncthreads();
        int exc = woff[wv] + inc - v;
        if (b < NBUCK) {
            lstart[b] = exc;
            if (v > 0) gbase[b] = atomicAdd(&bucket_cursor[b], v);
        }
    }
    __syncthreads();
    // scatter into LDS, grouped by bucket
#pragma unroll
    for (int i = 0; i < 16; ++i) {
        if (rows[i] >= 0) {
            int b = rows[i] >> BSHIFT;
            int p = lstart[b] + loff[i];
            lrow[p] = rows[i];
            lcv[p]  = cv[i];
        }
    }
    __syncthreads();
    const int total = lstart[NBUCK - 1] + cnt[NBUCK - 1];
    for (int p = tid; p < total; p += 256) {
        int r = lrow[p];
        int b = r >> BSHIFT;
        int g = gbase[b] + (p - lstart[b]);
        srow[g]    = r;
        scolval[g] = lcv[p];
    }
}

// ---------------- binned scatter pass 2: bucket staging -> row-ordered CSR ----------------
// One block per bucket: all writes land in one ~130KB window from one CU -> one XCD L2.
__global__ __launch_bounds__(256) void binpass2_kernel(const int* __restrict__ rowptr,
                                                       const int* __restrict__ srow,
                                                       const int2* __restrict__ scolval,
                                                       int* __restrict__ cursor,
                                                       int2* __restrict__ cedge) {
    const int b = blockIdx.x;
    const int lo = rowptr[b << BSHIFT];
    const int rhiidx = ((b + 1) << BSHIFT);
    const int hi = rowptr[rhiidx > N_NODES ? N_NODES : rhiidx];
    for (int k = lo + threadIdx.x; k < hi; k += 256) {
        int r = srow[k];
        int pos = atomicAdd(&cursor[r], 1);
        cedge[pos] = scolval[k];
    }
}

// ---------------- f32 -> bf16 elementwise ----------------
__global__ __launch_bounds__(256) void cvt_kernel(const float* __restrict__ in,
                                                  ushort* __restrict__ out, int n4) {
    int i = blockIdx.x * 256 + threadIdx.x;
    if (i < n4) {
        float4 v = ((const float4*)in)[i];
        uint2 p;
        p.x = (unsigned)f2b(v.x) | ((unsigned)f2b(v.y) << 16);
        p.y = (unsigned)f2b(v.z) | ((unsigned)f2b(v.w) << 16);
        ((uint2*)out)[i] = p;
    }
}

// ---------------- W [512][256] f32 -> Wt [256][512] bf16 (transpose) ----------------
__global__ __launch_bounds__(256) void wtrans_kernel(const float* __restrict__ W,
                                                     ushort* __restrict__ Wt) {
    int t = blockIdx.x * 256 + threadIdx.x;
    int j = t & 255;
    int k = t >> 8;
    Wt[(size_t)j * 512 + k] = f2b(W[(size_t)k * 256 + j]);
}

// ---------------- CSR SpMM (bf16 features): one wave per node ----------------
__global__ __launch_bounds__(256) void spmm_kernel(const int* __restrict__ rowptr,
                                                   const int2* __restrict__ cedge,
                                                   const ushort* __restrict__ h,
                                                   ushort* __restrict__ outb) {
    const int node = (blockIdx.x << 2) + (threadIdx.x >> 6);
    const int lane = threadIdx.x & 63;
    const uint2* __restrict__ h2 = (const uint2*)h;
    int k = rowptr[node];
    const int end = rowptr[node + 1];
    float a0 = 0.f, a1 = 0.f, a2 = 0.f, a3 = 0.f;
#define EDGE_FMA(e, d)                                              \
    {                                                               \
        float v = __int_as_float((e).y);                            \
        a0 = fmaf(v, __uint_as_float((d).x << 16), a0);             \
        a1 = fmaf(v, __uint_as_float((d).x & 0xffff0000u), a1);     \
        a2 = fmaf(v, __uint_as_float((d).y << 16), a2);             \
        a3 = fmaf(v, __uint_as_float((d).y & 0xffff0000u), a3);     \
    }
    for (; k + 4 <= end; k += 4) {
        int2 e0 = cedge[k];
        int2 e1 = cedge[k + 1];
        int2 e2 = cedge[k + 2];
        int2 e3 = cedge[k + 3];
        uint2 d0 = h2[(size_t)e0.x * 64 + lane];
        uint2 d1 = h2[(size_t)e1.x * 64 + lane];
        uint2 d2 = h2[(size_t)e2.x * 64 + lane];
        uint2 d3 = h2[(size_t)e3.x * 64 + lane];
        EDGE_FMA(e0, d0)
        EDGE_FMA(e1, d1)
        EDGE_FMA(e2, d2)
        EDGE_FMA(e3, d3)
    }
    for (; k < end; ++k) {
        int2 e = cedge[k];
        uint2 d = h2[(size_t)e.x * 64 + lane];
        EDGE_FMA(e, d)
    }
#undef EDGE_FMA
    uint2 p;
    p.x = (unsigned)f2b(a0) | ((unsigned)f2b(a1) << 16);
    p.y = (unsigned)f2b(a2) | ((unsigned)f2b(a3) << 16);
    ((uint2*)outb)[(size_t)node * 64 + lane] = p;
}

// ---------------- MFMA concat-GEMM ----------------
template <bool OUT_BF16>
__global__ __launch_bounds__(128) void gemm_mfma_kernel(const ushort* __restrict__ A1,
                                                        const ushort* __restrict__ A2,
                                                        const ushort* __restrict__ Wt,
                                                        const float* __restrict__ bias,
                                                        void* __restrict__ outp) {
    __shared__ float lds[2][16][260];
    const int wid  = threadIdx.x >> 6;
    const int lane = threadIdx.x & 63;
    const int wave = blockIdx.x * 2 + wid;
    const int row0 = wave * 16;
    const int lr = lane & 15;
    const int lk = (lane >> 4) * 8;

    f32x4 acc[16];
#pragma unroll
    for (int c = 0; c < 16; ++c) acc[c] = (f32x4){0.f, 0.f, 0.f, 0.f};

#pragma unroll 1
    for (int t8 = 0; t8 < 8; ++t8) {
        bf16x8 af = *(const bf16x8*)(A1 + (size_t)(row0 + lr) * 256 + t8 * 32 + lk);
#pragma unroll
        for (int c = 0; c < 16; ++c) {
            bf16x8 bf_ = *(const bf16x8*)(Wt + ((size_t)(c * 16 + lr) << 9) + t8 * 32 + lk);
            acc[c] = __builtin_amdgcn_mfma_f32_16x16x32_bf16(af, bf_, acc[c], 0, 0, 0);
        }
    }
#pragma unroll 1
    for (int t8 = 0; t8 < 8; ++t8) {
        bf16x8 af = *(const bf16x8*)(A2 + (size_t)(row0 + lr) * 256 + t8 * 32 + lk);
#pragma unroll
        for (int c = 0; c < 16; ++c) {
            bf16x8 bf_ = *(const bf16x8*)(Wt + ((size_t)(c * 16 + lr) << 9) + 256 + t8 * 32 + lk);
            acc[c] = __builtin_amdgcn_mfma_f32_16x16x32_bf16(af, bf_, acc[c], 0, 0, 0);
        }
    }

    float (*L)[260] = lds[wid];
#pragma unroll
    for (int c = 0; c < 16; ++c) {
        float bv = bias[c * 16 + lr];
#pragma unroll
        for (int r = 0; r < 4; ++r) {
            float v = acc[c][r] + bv;
            if (OUT_BF16) v = fmaxf(v, 0.f);
            L[(lane >> 4) * 4 + r][c * 16 + lr] = v;
        }
    }
    __syncthreads();
    if (OUT_BF16) {
        ushort* out = (ushort*)outp;
#pragma unroll
        for (int i = 0; i < 16; ++i) {
            float4 v = *(const float4*)&L[i][lane * 4];
            uint2 p;
            p.x = (unsigned)f2b(v.x) | ((unsigned)f2b(v.y) << 16);
            p.y = (unsigned)f2b(v.z) | ((unsigned)f2b(v.w) << 16);
            *(uint2*)&out[(size_t)(row0 + i) * 256 + lane * 4] = p;
        }
    } else {
        float* out = (float*)outp;
#pragma unroll
        for (int i = 0; i < 16; ++i) {
            float4 v = *(const float4*)&L[i][lane * 4];
            *(float4*)&out[(size_t)(row0 + i) * 256 + lane * 4] = v;
        }
    }
}

extern "C" void kernel_launch(void* const* d_in, const int* in_sizes, int n_in,
                              void* d_out, int out_size, void* d_ws, size_t ws_size,
                              hipStream_t stream) {
    const float* x     = (const float*)d_in[0];
    const int*   erow  = (const int*)d_in[1];
    const int*   ecol  = (const int*)d_in[2];
    const float* evalv = (const float*)d_in[3];
    const float* W1    = (const float*)d_in[4];
    const float* b1    = (const float*)d_in[5];
    const float* Wout  = (const float*)d_in[6];
    const float* bout  = (const float*)d_in[7];
    float* out = (float*)d_out;

    char* ws = (char*)d_ws;
    size_t off = 0;
    auto alloc = [&](size_t bytes) -> void* {
        void* p = ws + off;
        off += (bytes + 255) & ~(size_t)255;
        return p;
    };
    ushort* xb       = (ushort*)alloc((size_t)N_NODES * D * 2);     // 51.2 MB
    ushort* h1b      = (ushort*)alloc((size_t)N_NODES * D * 2);     // 51.2 MB
    ushort* neighb   = (ushort*)alloc((size_t)N_NODES * D * 2);     // 51.2 MB
    ushort* W1t      = (ushort*)alloc((size_t)512 * 256 * 2);
    ushort* Woutt    = (ushort*)alloc((size_t)512 * 256 * 2);
    int*    rowptr   = (int*)alloc((size_t)(N_NODES + 1) * sizeof(int));
    int*    deg      = (int*)alloc((size_t)N_NODES * sizeof(int));
    int*    cursor   = (int*)alloc((size_t)N_NODES * sizeof(int));
    int*    blocksum = (int*)alloc((size_t)SCAN_BLOCKS * sizeof(int));
    int*    bcursor  = (int*)alloc((size_t)NBUCK * sizeof(int));
    int*    srow     = (int*)alloc((size_t)N_EDGES * sizeof(int));      // 12.8 MB
    int2*   scolval  = (int2*)alloc((size_t)N_EDGES * sizeof(int2));    // 25.6 MB
    int2*   cedge    = (int2*)alloc((size_t)N_EDGES * sizeof(int2));    // 25.6 MB

    // converts (independent of CSR)
    cvt_kernel<<<(N_NODES * D / 4 + 255) / 256, 256, 0, stream>>>(x, xb, N_NODES * D / 4);
    wtrans_kernel<<<512, 256, 0, stream>>>(W1, W1t);
    wtrans_kernel<<<512, 256, 0, stream>>>(Wout, Woutt);

    // build CSR (reused by both SpMM layers)
    hipMemsetAsync(deg, 0, (size_t)N_NODES * sizeof(int), stream);
    hist_kernel<<<(N_EDGES + 255) / 256, 256, 0, stream>>>(erow, deg);
    scanA_kernel<<<SCAN_BLOCKS, 1024, 0, stream>>>(deg, rowptr, blocksum);
    scanB_kernel<<<1, 64, 0, stream>>>(blocksum, rowptr);
    scanC_kernel<<<SCAN_BLOCKS, 1024, 0, stream>>>(rowptr, blocksum, cursor);
    bucketinit_kernel<<<1, 256, 0, stream>>>(rowptr, bcursor);
    binpass1_kernel<<<(N_EDGES + EPB - 1) / EPB, 256, 0, stream>>>(erow, ecol, evalv,
                                                                   bcursor, srow, scolval);
    binpass2_kernel<<<NBUCK, 256, 0, stream>>>(rowptr, srow, scolval, cursor, cedge);

    // layer 1
    spmm_kernel<<<N_NODES / 4, 256, 0, stream>>>(rowptr, cedge, xb, neighb);
    gemm_mfma_kernel<true><<<N_NODES / 32, 128, 0, stream>>>(xb, neighb, W1t, b1, h1b);
    // layer 2
    spmm_kernel<<<N_NODES / 4, 256, 0, stream>>>(rowptr, cedge, h1b, neighb);
    gemm_mfma_kernel<false><<<N_NODES / 32, 128, 0, stream>>>(h1b, neighb, Woutt, bout, out);
}

// Round 6
// 980.073 us; speedup vs baseline: 2.3482x; 1.2073x over previous
//
#include <hip/hip_runtime.h>
#include <cstddef>
#include <cstdint>

#define N_NODES 100000
#define N_EDGES 3200000
#define D 256
#define SCAN_BLOCKS ((N_NODES + 1023) / 1024)  // 98
#define BSHIFT 9                                // 512 rows per bucket
#define NBUCK ((N_NODES + (1 << BSHIFT) - 1) >> BSHIFT)  // 196
#define EPB 4096                                // edges per pass-1 block

typedef __attribute__((ext_vector_type(8))) short bf16x8;
typedef __attribute__((ext_vector_type(4))) float f32x4;

#define GLOAD16(gsrc, ldst)                                                      \
    __builtin_amdgcn_global_load_lds(                                            \
        (const __attribute__((address_space(1))) void*)(gsrc),                   \
        (__attribute__((address_space(3))) void*)(ldst), 16, 0, 0)

__device__ __forceinline__ ushort f2b(float f) {  // f32 -> bf16 RNE
    unsigned u = __float_as_uint(f);
    return (ushort)((u + 0x7fffu + ((u >> 16) & 1u)) >> 16);
}

// ---------------- degree histogram ----------------
__global__ __launch_bounds__(256) void hist_kernel(const int* __restrict__ row,
                                                   int* __restrict__ deg) {
    int e = blockIdx.x * 256 + threadIdx.x;
    if (e < N_EDGES) atomicAdd(&deg[row[e]], 1);
}

// ---------------- scan stage A ----------------
__global__ __launch_bounds__(1024) void scanA_kernel(const int* __restrict__ deg,
                                                     int* __restrict__ rowptr,
                                                     int* __restrict__ blocksum) {
    __shared__ int waveTot[16];
    __shared__ int waveOff[16];
    const int tid  = threadIdx.x;
    const int lane = tid & 63;
    const int wv   = tid >> 6;
    const int idx  = blockIdx.x * 1024 + tid;
    int v = (idx < N_NODES) ? deg[idx] : 0;
    int inc = v;
#pragma unroll
    for (int off = 1; off < 64; off <<= 1) {
        int up = __shfl_up(inc, off, 64);
        if (lane >= off) inc += up;
    }
    if (lane == 63) waveTot[wv] = inc;
    __syncthreads();
    if (tid == 0) {
        int run = 0;
#pragma unroll
        for (int w = 0; w < 16; ++w) { waveOff[w] = run; run += waveTot[w]; }
        blocksum[blockIdx.x] = run;
    }
    __syncthreads();
    if (idx < N_NODES) rowptr[idx] = waveOff[wv] + (inc - v);
}

// ---------------- scan stage B ----------------
__global__ void scanB_kernel(int* __restrict__ blocksum, int* __restrict__ rowptr) {
    if (threadIdx.x == 0 && blockIdx.x == 0) {
        int run = 0;
        for (int b = 0; b < SCAN_BLOCKS; ++b) {
            int t = blocksum[b];
            blocksum[b] = run;
            run += t;
        }
        rowptr[N_NODES] = run;
    }
}

// ---------------- scan stage C ----------------
__global__ __launch_bounds__(1024) void scanC_kernel(int* __restrict__ rowptr,
                                                     const int* __restrict__ blocksum,
                                                     int* __restrict__ cursor) {
    const int idx = blockIdx.x * 1024 + threadIdx.x;
    if (idx < N_NODES) {
        int v = rowptr[idx] + blocksum[blockIdx.x];
        rowptr[idx] = v;
        cursor[idx] = v;
    }
}

// ---------------- bucket cursor init ----------------
__global__ void bucketinit_kernel(const int* __restrict__ rowptr,
                                  int* __restrict__ bucket_cursor) {
    int b = blockIdx.x * 256 + threadIdx.x;
    if (b < NBUCK) bucket_cursor[b] = rowptr[b << BSHIFT];
}

// ---------------- binned scatter pass 1 ----------------
__global__ __launch_bounds__(256) void binpass1_kernel(const int* __restrict__ erow,
                                                       const int* __restrict__ ecol,
                                                       const float* __restrict__ evalv,
                                                       int* __restrict__ bucket_cursor,
                                                       int* __restrict__ srow,
                                                       int2* __restrict__ scolval) {
    __shared__ int cnt[NBUCK];
    __shared__ int lstart[NBUCK];
    __shared__ int gbase[NBUCK];
    __shared__ int wtot[4];
    __shared__ int woff[4];
    __shared__ int   lrow[EPB];   // 16 KB
    __shared__ int2  lcv[EPB];    // 32 KB
    const int tid = threadIdx.x;
    const size_t base = (size_t)blockIdx.x * EPB;
    for (int b = tid; b < NBUCK; b += 256) cnt[b] = 0;
    __syncthreads();
    int rows[16];
    int2 cv[16];
    int loff[16];
#pragma unroll
    for (int i = 0; i < 16; ++i) {
        size_t e = base + (size_t)i * 256 + tid;
        if (e < N_EDGES) {
            int r = erow[e];
            rows[i] = r;
            cv[i] = make_int2(ecol[e], __float_as_int(evalv[e]));
            loff[i] = atomicAdd(&cnt[r >> BSHIFT], 1);
        } else {
            rows[i] = -1;
        }
    }
    __syncthreads();
    {
        int b = tid;
        int v = (b < NBUCK) ? cnt[b] : 0;
        int lane = tid & 63, wv = tid >> 6;
        int inc = v;
#pragma unroll
        for (int off = 1; off < 64; off <<= 1) {
            int u = __shfl_up(inc, off, 64);
            if (lane >= off) inc += u;
        }
        if (lane == 63) wtot[wv] = inc;
        __syncthreads();
        if (tid == 0) {
            int run = 0;
#pragma unroll
            for (int w = 0; w < 4; ++w) { woff[w] = run; run += wtot[w]; }
        }
        __syncthreads();
        int exc = woff[wv] + inc - v;
        if (b < NBUCK) {
            lstart[b] = exc;
            if (v > 0) gbase[b] = atomicAdd(&bucket_cursor[b], v);
        }
    }
    __syncthreads();
#pragma unroll
    for (int i = 0; i < 16; ++i) {
        if (rows[i] >= 0) {
            int b = rows[i] >> BSHIFT;
            int p = lstart[b] + loff[i];
            lrow[p] = rows[i];
            lcv[p]  = cv[i];
        }
    }
    __syncthreads();
    const int total = lstart[NBUCK - 1] + cnt[NBUCK - 1];
    for (int p = tid; p < total; p += 256) {
        int r = lrow[p];
        int b = r >> BSHIFT;
        int g = gbase[b] + (p - lstart[b]);
        srow[g]    = r;
        scolval[g] = lcv[p];
    }
}

// ---------------- binned scatter pass 2 ----------------
__global__ __launch_bounds__(256) void binpass2_kernel(const int* __restrict__ rowptr,
                                                       const int* __restrict__ srow,
                                                       const int2* __restrict__ scolval,
                                                       int* __restrict__ cursor,
                                                       int2* __restrict__ cedge) {
    const int b = blockIdx.x;
    const int lo = rowptr[b << BSHIFT];
    const int rhiidx = ((b + 1) << BSHIFT);
    const int hi = rowptr[rhiidx > N_NODES ? N_NODES : rhiidx];
    for (int k = lo + threadIdx.x; k < hi; k += 256) {
        int r = srow[k];
        int pos = atomicAdd(&cursor[r], 1);
        cedge[pos] = scolval[k];
    }
}

// ---------------- f32 -> bf16 elementwise ----------------
__global__ __launch_bounds__(256) void cvt_kernel(const float* __restrict__ in,
                                                  ushort* __restrict__ out, int n4) {
    int i = blockIdx.x * 256 + threadIdx.x;
    if (i < n4) {
        float4 v = ((const float4*)in)[i];
        uint2 p;
        p.x = (unsigned)f2b(v.x) | ((unsigned)f2b(v.y) << 16);
        p.y = (unsigned)f2b(v.z) | ((unsigned)f2b(v.w) << 16);
        ((uint2*)out)[i] = p;
    }
}

// ---------------- W [512][256] f32 -> Wt [256][512] bf16 (transpose) ----------------
__global__ __launch_bounds__(256) void wtrans_kernel(const float* __restrict__ W,
                                                     ushort* __restrict__ Wt) {
    int t = blockIdx.x * 256 + threadIdx.x;
    int j = t & 255;
    int k = t >> 8;
    Wt[(size_t)j * 512 + k] = f2b(W[(size_t)k * 256 + j]);
}

// ---------------- CSR SpMM (bf16 features): one wave per node ----------------
__global__ __launch_bounds__(256) void spmm_kernel(const int* __restrict__ rowptr,
                                                   const int2* __restrict__ cedge,
                                                   const ushort* __restrict__ h,
                                                   ushort* __restrict__ outb) {
    const int node = (blockIdx.x << 2) + (threadIdx.x >> 6);
    const int lane = threadIdx.x & 63;
    const uint2* __restrict__ h2 = (const uint2*)h;
    int k = rowptr[node];
    const int end = rowptr[node + 1];
    float a0 = 0.f, a1 = 0.f, a2 = 0.f, a3 = 0.f;
#define EDGE_FMA(e, d)                                              \
    {                                                               \
        float v = __int_as_float((e).y);                            \
        a0 = fmaf(v, __uint_as_float((d).x << 16), a0);             \
        a1 = fmaf(v, __uint_as_float((d).x & 0xffff0000u), a1);     \
        a2 = fmaf(v, __uint_as_float((d).y << 16), a2);             \
        a3 = fmaf(v, __uint_as_float((d).y & 0xffff0000u), a3);     \
    }
    for (; k + 4 <= end; k += 4) {
        int2 e0 = cedge[k];
        int2 e1 = cedge[k + 1];
        int2 e2 = cedge[k + 2];
        int2 e3 = cedge[k + 3];
        uint2 d0 = h2[(size_t)e0.x * 64 + lane];
        uint2 d1 = h2[(size_t)e1.x * 64 + lane];
        uint2 d2 = h2[(size_t)e2.x * 64 + lane];
        uint2 d3 = h2[(size_t)e3.x * 64 + lane];
        EDGE_FMA(e0, d0)
        EDGE_FMA(e1, d1)
        EDGE_FMA(e2, d2)
        EDGE_FMA(e3, d3)
    }
    for (; k < end; ++k) {
        int2 e = cedge[k];
        uint2 d = h2[(size_t)e.x * 64 + lane];
        EDGE_FMA(e, d)
    }
#undef EDGE_FMA
    uint2 p;
    p.x = (unsigned)f2b(a0) | ((unsigned)f2b(a1) << 16);
    p.y = (unsigned)f2b(a2) | ((unsigned)f2b(a3) << 16);
    ((uint2*)outb)[(size_t)node * 64 + lane] = p;
}

// ---------------- MFMA concat-GEMM, LDS-staged (m97 2-barrier structure) ----------
// C[M,256] = act([A1|A2] @ W + bias). Block: BM=64 rows x BN=256 cols, BK=64,
// 4 waves; wave w owns 64x64 sub-tile (cols w*64..w*64+63), 4x4 frags of
// mfma_f32_16x16x32_bf16. A-tile (8KB) + B-tile (32KB) staged per K-step via
// global_load_lds(16B) with PRE-SWIZZLED global source; frag reads swizzle the
// FULL 3-bit chunk index: phys_chunk = logical_chunk ^ (row&7). kk advances via
// XOR (bit 6), NOT add — add would carry into the row bits for lr&4 lanes.
template <bool OUT_BF16>
__global__ __launch_bounds__(256, 2) void gemm_mfma_kernel(const ushort* __restrict__ A1,
                                                           const ushort* __restrict__ A2,
                                                           const ushort* __restrict__ Wt,
                                                           const float* __restrict__ bias,
                                                           void* __restrict__ outp) {
    __shared__ __align__(16) char lds[40960];  // As 0..8191, Bs 8192..40959
    const int tid  = threadIdx.x;
    const int wid  = tid >> 6;
    const int lane = tid & 63;
    const int lr   = lane & 15;
    const int g    = lane >> 4;
    const int bm   = blockIdx.x * 64;

    // ---- staging source precompute (inverse-swizzled global addresses) ----
    const int l3  = lane >> 3;                 // 0..7 (row within 8-row slot)
    const int cL  = ((lane & 7) ^ l3) * 8;     // logical 8-elem chunk for this slot
    int rowA[2];
#pragma unroll
    for (int p = 0; p < 2; ++p) {
        int r = (p * 4 + wid) * 8 + l3;        // 0..63
        int gr = bm + r;
        rowA[p] = gr < N_NODES ? gr : N_NODES - 1;
    }
    // B: slot s=p*4+wid -> Wt row = s*8 + l3 = p*32 + wid*8 + l3
    const ushort* wB = Wt + ((size_t)(wid * 8 + l3) << 9) + cL;  // + p*16384 + t*64

    // ---- frag read offsets (swizzled, kk=0 half; kk=1 = ^64) ----
    int aoffs[4], boffs[4];
#pragma unroll
    for (int f = 0; f < 4; ++f) {
        aoffs[f] = (((f * 16 + lr) * 128 + g * 16) ^ ((lr & 7) << 4));
        boffs[f] = 8192 + (((wid * 64 + f * 16 + lr) * 128 + g * 16) ^ ((lr & 7) << 4));
    }

    f32x4 acc[4][4];
#pragma unroll
    for (int i = 0; i < 4; ++i)
#pragma unroll
        for (int j = 0; j < 4; ++j) acc[i][j] = (f32x4){0.f, 0.f, 0.f, 0.f};

#pragma unroll 1
    for (int t = 0; t < 8; ++t) {
        const ushort* __restrict__ Ab = (t < 4) ? A1 : A2;
        const int k0 = (t & 3) * 64;
        // stage A (2 x 1KB per wave) + B (8 x 1KB per wave)
#pragma unroll
        for (int p = 0; p < 2; ++p)
            GLOAD16(Ab + (size_t)rowA[p] * 256 + k0 + cL, lds + (p * 4 + wid) * 1024);
#pragma unroll
        for (int p = 0; p < 8; ++p)
            GLOAD16(wB + p * 16384 + t * 64, lds + 8192 + (p * 4 + wid) * 1024);
        __syncthreads();  // drains vmcnt(0) then barrier
#pragma unroll
        for (int kk = 0; kk < 2; ++kk) {
            const int kx = kk << 6;  // advance k-half by XOR (bit 6), not add
            bf16x8 bfr[4];
#pragma unroll
            for (int fc = 0; fc < 4; ++fc)
                bfr[fc] = *(const bf16x8*)(lds + (boffs[fc] ^ kx));
#pragma unroll
            for (int fr = 0; fr < 4; ++fr) {
                bf16x8 af = *(const bf16x8*)(lds + (aoffs[fr] ^ kx));
#pragma unroll
                for (int fc = 0; fc < 4; ++fc)
                    acc[fr][fc] = __builtin_amdgcn_mfma_f32_16x16x32_bf16(af, bfr[fc],
                                                                          acc[fr][fc], 0, 0, 0);
            }
        }
        __syncthreads();  // compute done before next stage overwrites
    }

    float bv[4];
#pragma unroll
    for (int fc = 0; fc < 4; ++fc) bv[fc] = bias[wid * 64 + fc * 16 + lr];

    if (!OUT_BF16) {
        // direct f32 stores (64B segments per lane-group)
        float* out = (float*)outp;
#pragma unroll
        for (int fr = 0; fr < 4; ++fr)
#pragma unroll
            for (int reg = 0; reg < 4; ++reg) {
                int row = bm + fr * 16 + g * 4 + reg;
                if (row < N_NODES) {
#pragma unroll
                    for (int fc = 0; fc < 4; ++fc)
                        out[(size_t)row * 256 + wid * 64 + fc * 16 + lr] =
                            acc[fr][fc][reg] + bv[fc];
                }
            }
    } else {
        // relu + bf16 pack via LDS repack (two 32-row halves)
        ushort* out = (ushort*)outp;
        float (*L)[260] = (float(*)[260])lds;
#pragma unroll 1
        for (int half = 0; half < 2; ++half) {
            __syncthreads();
#pragma unroll
            for (int fr2 = 0; fr2 < 2; ++fr2) {
                int fr = half * 2 + fr2;
#pragma unroll
                for (int fc = 0; fc < 4; ++fc)
#pragma unroll
                    for (int reg = 0; reg < 4; ++reg) {
                        int r = fr2 * 16 + g * 4 + reg;
                        L[r][wid * 64 + fc * 16 + lr] = fmaxf(acc[fr][fc][reg] + bv[fc], 0.f);
                    }
            }
            __syncthreads();
            int r  = tid >> 3;
            int ch = tid & 7;
            int grow = bm + half * 32 + r;
            if (grow < N_NODES) {
#pragma unroll
                for (int q = 0; q < 4; ++q) {
                    float4 u0 = *(const float4*)&L[r][ch * 32 + q * 8];
                    float4 u1 = *(const float4*)&L[r][ch * 32 + q * 8 + 4];
                    uint2 pk;
                    pk.x = (unsigned)f2b(u0.x) | ((unsigned)f2b(u0.y) << 16);
                    pk.y = (unsigned)f2b(u0.z) | ((unsigned)f2b(u0.w) << 16);
                    uint2 pk2;
                    pk2.x = (unsigned)f2b(u1.x) | ((unsigned)f2b(u1.y) << 16);
                    pk2.y = (unsigned)f2b(u1.z) | ((unsigned)f2b(u1.w) << 16);
                    uint4 w4 = make_uint4(pk.x, pk.y, pk2.x, pk2.y);
                    *(uint4*)&out[(size_t)grow * 256 + ch * 32 + q * 8] = w4;
                }
            }
        }
    }
}

extern "C" void kernel_launch(void* const* d_in, const int* in_sizes, int n_in,
                              void* d_out, int out_size, void* d_ws, size_t ws_size,
                              hipStream_t stream) {
    const float* x     = (const float*)d_in[0];
    const int*   erow  = (const int*)d_in[1];
    const int*   ecol  = (const int*)d_in[2];
    const float* evalv = (const float*)d_in[3];
    const float* W1    = (const float*)d_in[4];
    const float* b1    = (const float*)d_in[5];
    const float* Wout  = (const float*)d_in[6];
    const float* bout  = (const float*)d_in[7];
    float* out = (float*)d_out;

    char* ws = (char*)d_ws;
    size_t off = 0;
    auto alloc = [&](size_t bytes) -> void* {
        void* p = ws + off;
        off += (bytes + 255) & ~(size_t)255;
        return p;
    };
    ushort* xb       = (ushort*)alloc((size_t)N_NODES * D * 2);     // 51.2 MB
    ushort* h1b      = (ushort*)alloc((size_t)N_NODES * D * 2);     // 51.2 MB
    ushort* neighb   = (ushort*)alloc((size_t)N_NODES * D * 2);     // 51.2 MB
    ushort* W1t      = (ushort*)alloc((size_t)512 * 256 * 2);
    ushort* Woutt    = (ushort*)alloc((size_t)512 * 256 * 2);
    int*    rowptr   = (int*)alloc((size_t)(N_NODES + 1) * sizeof(int));
    int*    deg      = (int*)alloc((size_t)N_NODES * sizeof(int));
    int*    cursor   = (int*)alloc((size_t)N_NODES * sizeof(int));
    int*    blocksum = (int*)alloc((size_t)SCAN_BLOCKS * sizeof(int));
    int*    bcursor  = (int*)alloc((size_t)NBUCK * sizeof(int));
    int*    srow     = (int*)alloc((size_t)N_EDGES * sizeof(int));      // 12.8 MB
    int2*   scolval  = (int2*)alloc((size_t)N_EDGES * sizeof(int2));    // 25.6 MB
    int2*   cedge    = (int2*)alloc((size_t)N_EDGES * sizeof(int2));    // 25.6 MB

    // converts (independent of CSR)
    cvt_kernel<<<(N_NODES * D / 4 + 255) / 256, 256, 0, stream>>>(x, xb, N_NODES * D / 4);
    wtrans_kernel<<<512, 256, 0, stream>>>(W1, W1t);
    wtrans_kernel<<<512, 256, 0, stream>>>(Wout, Woutt);

    // build CSR (reused by both SpMM layers)
    hipMemsetAsync(deg, 0, (size_t)N_NODES * sizeof(int), stream);
    hist_kernel<<<(N_EDGES + 255) / 256, 256, 0, stream>>>(erow, deg);
    scanA_kernel<<<SCAN_BLOCKS, 1024, 0, stream>>>(deg, rowptr, blocksum);
    scanB_kernel<<<1, 64, 0, stream>>>(blocksum, rowptr);
    scanC_kernel<<<SCAN_BLOCKS, 1024, 0, stream>>>(rowptr, blocksum, cursor);
    bucketinit_kernel<<<1, 256, 0, stream>>>(rowptr, bcursor);
    binpass1_kernel<<<(N_EDGES + EPB - 1) / EPB, 256, 0, stream>>>(erow, ecol, evalv,
                                                                   bcursor, srow, scolval);
    binpass2_kernel<<<NBUCK, 256, 0, stream>>>(rowptr, srow, scolval, cursor, cedge);

    const int gblocks = (N_NODES + 63) / 64;  // 1563
    // layer 1
    spmm_kernel<<<N_NODES / 4, 256, 0, stream>>>(rowptr, cedge, xb, neighb);
    gemm_mfma_kernel<true><<<gblocks, 256, 0, stream>>>(xb, neighb, W1t, b1, h1b);
    // layer 2
    spmm_kernel<<<N_NODES / 4, 256, 0, stream>>>(rowptr, cedge, h1b, neighb);
    gemm_mfma_kernel<false><<<gblocks, 256, 0, stream>>>(h1b, neighb, Woutt, bout, out);
}